// Round 8
// baseline (352.383 us; speedup 1.0000x reference)
//
#include <hip/hip_runtime.h>

// SSIM3D, (4,1,128,128,128) fp32, separable 11-tap Gaussian, scalar mean out.
//
// R14: 1-WAVE BLOCKS (the residency fix). R13 post-mortem: halving DS reads
// changed nothing (76us); VALUBusy 42% at 1083 cyc wall per wave-step means
// effective residency ~1.2 waves/SIMD -- matches OccupancyPercent 15%. The
// occupancy has tracked launch_bounds arg2 all session (2->15%,3->23%,
// 4->41%): arg2 is min BLOCKS/EU (CUDA semantics), so (128,2) requested only
// ~4 waves/EU AND the HW delivered ~1.2. Both kernels are fully per-wave
// independent (per-wave private LDS ring; B waves only met at a 4-way add),
// so: 64-thread blocks, __launch_bounds__(64,4) -> VGPR cap 512/4=128 (the
// proven no-spill budget, R13=120 VGPR) with 4 waves/SIMD = 512 regs exact.
// A: grid 4096 (half-row per block). B: grid 4096, LDS+syncthreads deleted,
// per-wave sums to partials[4096]. Per-thread math/order bit-identical.
// Invariant: ssimA WRITE_SIZE == 163840 KB (no scratch).

#define SLICE (128*128)        // 16384
#define S  (128*SLICE)         // 2097152 per field per batch
#define ZROW 640               // 5 fields * 128 x  (interleaved row)
#define ZSL  81920             // 128 y * ZROW      (interleaved slice)
#define C1_ 0.0001f
#define C2_ 0.0009f

__device__ __forceinline__ void make_g_s(float* gs) {
    float g[11]; float s = 0.f;
#pragma unroll
    for (int i = 0; i < 11; ++i) {
        float d = (float)(i - 5);
        g[i] = __expf(-d * d / 4.5f);
        s += g[i];
    }
    float inv = 1.f / s;
#pragma unroll
    for (int i = 0; i < 11; ++i)
        gs[i] = __int_as_float(__builtin_amdgcn_readfirstlane(
                    __float_as_int(g[i] * inv)));
}

// ---------------- Kernel A: x-conv + y-conv, walk y ----------------
// grid: 4n * 128z * 4yc * 2half = 4096 blocks of 64 threads (1 wave).
// Wave owns x-half [64h, 64h+63] of one (z, yc); walks 32 y outputs (42 input
// rows). LDS ring: 2 slots x (img1 row | img2 row), full 128-col rows padded
// to 160 floats (data at dwords [8..135], zeros outside): maskless taps.
#define RB    160              // dwords per padded row
#define RSLOT (2*RB)           // 320 dwords per ring slot
#define WRING (2*RSLOT)        // 640 dwords per ring (2 slots) = 2560 B

// One pipeline step. T_ runtime step index, TM_ compile-time (== T_ mod 11),
// J0_/J1_ compile-time y-tap range, RPE_/WPE_ read/write slot pointers.
// x-conv: 6 aligned float2 pairs per row, loaded and consumed immediately.
#define STEPA(T_, TM_, J0_, J1_, STORE_, OKC_, RPE_, WPE_) do {               \
    const int T__ = (T_);                                                     \
    int sp__ = T__ + 3; if (sp__ > 41) sp__ = 41;                             \
    int rowc__ = min(max(y0 + sp__ - 5, 0), 127);                             \
    float4 Rn__ = *(const float4*)(src + (size_t)rowc__ * 128);               \
    if (OKC_) {                                                               \
        const float* rp__ = (RPE_);                                           \
        float u1__ = 0.f, u2__ = 0.f, a11__ = 0.f, a22__ = 0.f, a12__ = 0.f;  \
        _Pragma("unroll")                                                     \
        for (int j = 0; j < 6; ++j) {                                         \
            float2 va__ = *(const float2*)(rp__ + 2 * j);                     \
            float2 vb__ = *(const float2*)(rp__ + RB + 2 * j);                \
            {                                                                 \
                float wj__ = w12[2 * j];                                      \
                float ta__ = wj__ * va__.x, tb__ = wj__ * vb__.x;             \
                u1__ += ta__; u2__ += tb__;                                   \
                a11__ = fmaf(ta__, va__.x, a11__);                            \
                a12__ = fmaf(ta__, vb__.x, a12__);                            \
                a22__ = fmaf(tb__, vb__.x, a22__);                            \
            }                                                                 \
            {                                                                 \
                float wj__ = w12[2 * j + 1];                                  \
                float ta__ = wj__ * va__.y, tb__ = wj__ * vb__.y;             \
                u1__ += ta__; u2__ += tb__;                                   \
                a11__ = fmaf(ta__, va__.y, a11__);                            \
                a12__ = fmaf(ta__, vb__.y, a12__);                            \
                a22__ = fmaf(tb__, vb__.y, a22__);                            \
            }                                                                 \
        }                                                                     \
        _Pragma("unroll")                                                     \
        for (int j = (J0_); j <= (J1_); ++j) {                                \
            const int sl__ = ((TM_) + j + 1) % 11;                            \
            float wy__ = gs[10 - j];                                          \
            acc[0][sl__] = fmaf(wy__, u1__,  acc[0][sl__]);                   \
            acc[1][sl__] = fmaf(wy__, u2__,  acc[1][sl__]);                   \
            acc[2][sl__] = fmaf(wy__, a11__, acc[2][sl__]);                   \
            acc[3][sl__] = fmaf(wy__, a22__, acc[3][sl__]);                   \
            acc[4][sl__] = fmaf(wy__, a12__, acc[4][sl__]);                   \
        }                                                                     \
    }                                                                         \
    *(float4*)(WPE_) = h1;          /* stage row T+1 (loaded 3 steps ago) */  \
    if (STORE_) {                                                             \
        size_t wo__ = (size_t)(y0 + T__ - 10) * ZROW;                         \
        const int es__ = ((TM_) + 1) % 11;                                    \
        _Pragma("unroll")                                                     \
        for (int f = 0; f < 5; ++f) {                                         \
            fb[wo__ + f * 128] = acc[f][es__];                                \
            acc[f][es__] = 0.f;                                               \
        }                                                                     \
    }                                                                         \
    h1 = h2; h2 = Rn__;                                                       \
} while (0)

__global__ __launch_bounds__(64, 4)
void ssimA(const float* __restrict__ img1, const float* __restrict__ img2,
           float* __restrict__ fields) {
    __shared__ __align__(16) float ring[WRING];   // 2560 B, one wave
    float gs[11]; make_g_s(gs);
    const int l = threadIdx.x;                 // lane 0..63
    const int b = blockIdx.x;
    const int half = b & 1, yc = (b >> 1) & 3, z = (b >> 3) & 127, n = b >> 10;
    const int x = (half << 6) + l;             // output column 0..127
    const int y0 = yc * 32;
    // lanes 0-31 stage the full img1 row (float4 each), lanes 32-63 img2 row
    const float* src = (l < 32 ? img1 : img2)
                     + (size_t)n * S + (size_t)z * SLICE + 4 * (l & 31);
    float* fb = fields + (size_t)(n * 128 + z) * ZSL + x;

    // per-parity 12-tap weights over the aligned window [e, e+11],
    // e = (x-5)&~1, p = (x-5)&1; tap k has weight g[k-p] (0 outside 0..10).
    const int p = (x - 5) & 1;
    const int e = (x - 5) - p;                 // even, in [-6, 122]
    float w12[12];
#pragma unroll
    for (int k = 0; k < 12; ++k) {
        float we = (k <= 10) ? gs[k] : 0.f;            // p == 0
        float wo = (k >= 1) ? gs[k - 1] : 0.f;         // p == 1
        w12[k] = p ? wo : we;
    }

    float* p_rd = ring + (8 + e);              // aligned window base (8B)
    float* p_wr = ring + ((l < 32) ? 0 : RB) + 8 + 4 * (l & 31);

    // zero whole ring once: pads stay zero forever (x-boundary = free)
    for (int i = l; i < WRING; i += 64) ring[i] = 0.f;

    float acc[5][11];
#pragma unroll
    for (int f = 0; f < 5; ++f)
#pragma unroll
        for (int s2 = 0; s2 < 11; ++s2) acc[f][s2] = 0.f;

    // prologue: rows for steps 0,1,2; slot0 written, rows 1,2 held in regs
    float4 h1, h2;
    {
        int r0 = min(max(y0 - 5, 0), 127);
        int r1 = min(max(y0 - 4, 0), 127);
        int r2 = min(max(y0 - 3, 0), 127);
        float4 R0 = *(const float4*)(src + (size_t)r0 * 128);
        h1        = *(const float4*)(src + (size_t)r1 * 128);
        h2        = *(const float4*)(src + (size_t)r2 * 128);
        *(float4*)(p_wr) = R0;                 // slot 0
    }

    // head: t = 0..9 (partial y-window, row may be < 0; no stores)
#pragma unroll
    for (int t = 0; t < 10; ++t) {
        STEPA(t, t, 10 - t, 10, false, (y0 + t - 5 >= 0),
              p_rd + (t & 1) * RSLOT, p_wr + ((t + 1) & 1) * RSLOT);
    }
    // steady: t = 10..31 -- branch-free, full window, store every step
    {
        int ro = 0, wro = RSLOT;               // slot(10)=0, slot(11)=1
#pragma unroll 1
        for (int blk = 0; blk < 2; ++blk) {
#pragma unroll
            for (int tt = 0; tt < 11; ++tt) {
                STEPA(10 + blk * 11 + tt, 10 + tt, 0, 10, true, true,
                      p_rd + ro, p_wr + wro);
                ro ^= RSLOT; wro ^= RSLOT;
            }
        }
    }
    // drain: t = 32..41 (partial y-window, row may be > 127; store always)
#pragma unroll
    for (int t = 32; t < 42; ++t) {
        STEPA(t, t % 11, 0, 41 - t, true, (y0 + t - 5 < 128),
              p_rd + (t & 1) * RSLOT, p_wr + ((t + 1) & 1) * RSLOT);
    }
}

// ---------------- Kernel B: z-conv + map + reduce, walk z ----------------
// grid: 4n * 128y * 2xh * 4zc = 4096 blocks of 64 threads (1 wave).
// Wave owns x-half of one y; walks 32 z outputs. Batches reversed (freshest
// A output first -> L3 hits). Depth-4 prefetch; interleaved layout puts the
// 5 per-step loads in one 2560 B cluster. No LDS, no syncthreads.
#define STEPB(T_, TM_, J0_, J1_, STORE_, OKC_) do {                           \
    const int T__ = (T_);                                                     \
    int sp__ = T__ + 4; if (sp__ > 41) sp__ = 41;                             \
    size_t off__ = (size_t)min(max(z0 + sp__ - 5, 0), 127) * ZSL;             \
    float N0__ = base[off__];                                                 \
    float N1__ = base[off__ + 128];                                           \
    float N2__ = base[off__ + 256];                                           \
    float N3__ = base[off__ + 384];                                           \
    float N4__ = base[off__ + 512];                                           \
    if (OKC_) {                                                               \
        _Pragma("unroll")                                                     \
        for (int j = (J0_); j <= (J1_); ++j) {                                \
            const int sl__ = ((TM_) + j + 1) % 11;                            \
            float wz__ = gs[10 - j];                                          \
            acc[0][sl__] = fmaf(wz__, P0[0], acc[0][sl__]);                   \
            acc[1][sl__] = fmaf(wz__, P0[1], acc[1][sl__]);                   \
            acc[2][sl__] = fmaf(wz__, P0[2], acc[2][sl__]);                   \
            acc[3][sl__] = fmaf(wz__, P0[3], acc[3][sl__]);                   \
            acc[4][sl__] = fmaf(wz__, P0[4], acc[4][sl__]);                   \
        }                                                                     \
    }                                                                         \
    if (STORE_) {                                                             \
        const int es__ = ((TM_) + 1) % 11;                                    \
        float m1__ = acc[0][es__], m2__ = acc[1][es__];                       \
        float p11__ = acc[2][es__], p22__ = acc[3][es__], p12__ = acc[4][es__];\
        float m1s__ = m1__ * m1__, m2s__ = m2__ * m2__, m12__ = m1__ * m2__;  \
        float v1c__ = p11__ - m1s__, v2c__ = p22__ - m2s__, cv__ = p12__ - m12__;\
        float num__ = (2.f * m12__ + C1_) * (2.f * cv__ + C2_);               \
        float den__ = (m1s__ + m2s__ + C1_) * (v1c__ + v2c__ + C2_);          \
        sum += num__ / den__;                                                 \
        _Pragma("unroll")                                                     \
        for (int f = 0; f < 5; ++f) acc[f][es__] = 0.f;                       \
    }                                                                         \
    _Pragma("unroll")                                                         \
    for (int f = 0; f < 5; ++f) { P0[f] = P1[f]; P1[f] = P2[f]; P2[f] = P3[f]; } \
    P3[0] = N0__; P3[1] = N1__; P3[2] = N2__; P3[3] = N3__; P3[4] = N4__;     \
} while (0)

__global__ __launch_bounds__(64, 4)
void ssimB(const float* __restrict__ fields, float* __restrict__ partials) {
    float gs[11]; make_g_s(gs);
    const int l = threadIdx.x;
    const int b = blockIdx.x;
    const int xh = b & 1, y = (b >> 1) & 127, zc = (b >> 8) & 3;
    const int n = 3 - (b >> 10);                // reverse batches (L3 hits)
    const int x = (xh << 6) + l;
    const int z0 = zc * 32;
    const float* base = fields + (size_t)n * 128 * ZSL + (size_t)y * ZROW + x;

    float acc[5][11];
#pragma unroll
    for (int f = 0; f < 5; ++f)
#pragma unroll
        for (int s2 = 0; s2 < 11; ++s2) acc[f][s2] = 0.f;

    float sum = 0.f;

    // depth-4 prologue: slices for steps 0..3
    float P0[5], P1[5], P2[5], P3[5];
    {
        size_t o0 = (size_t)min(max(z0 - 5, 0), 127) * ZSL;
        size_t o1 = (size_t)min(max(z0 - 4, 0), 127) * ZSL;
        size_t o2 = (size_t)min(max(z0 - 3, 0), 127) * ZSL;
        size_t o3 = (size_t)min(max(z0 - 2, 0), 127) * ZSL;
#pragma unroll
        for (int f = 0; f < 5; ++f) {
            P0[f] = base[o0 + f * 128];
            P1[f] = base[o1 + f * 128];
            P2[f] = base[o2 + f * 128];
            P3[f] = base[o3 + f * 128];
        }
    }

    // head: t = 0..9
#pragma unroll
    for (int t = 0; t < 10; ++t) {
        STEPB(t, t, 10 - t, 10, false, (z0 + t - 5 >= 0));
    }
    // steady: t = 10..31 -- branch-free
#pragma unroll 1
    for (int blk = 0; blk < 2; ++blk) {
#pragma unroll
        for (int tt = 0; tt < 11; ++tt) {
            STEPB(10 + blk * 11 + tt, 10 + tt, 0, 10, true, true);
        }
    }
    // drain: t = 32..41
#pragma unroll
    for (int t = 32; t < 42; ++t) {
        STEPB(t, t % 11, 0, 41 - t, true, (z0 + t - 5 < 128));
    }

    // single-wave reduce, straight to partials
#pragma unroll
    for (int o = 32; o > 0; o >>= 1) sum += __shfl_down(sum, o, 64);
    if (l == 0) partials[blockIdx.x] = sum;
}

// ---------------- final reduce ----------------
__global__ void ssim_final(const float* __restrict__ partial, int n,
                           float* __restrict__ out, double inv_count) {
    int tid = threadIdx.x;
    double s = 0.0;
    for (int i = tid; i < n; i += 256) s += (double)partial[i];
#pragma unroll
    for (int o = 32; o > 0; o >>= 1) s += __shfl_down(s, o, 64);
    __shared__ double wsum[4];
    int lane = tid & 63, wid = tid >> 6;
    if (lane == 0) wsum[wid] = s;
    __syncthreads();
    if (tid == 0)
        out[0] = (float)((wsum[0] + wsum[1] + wsum[2] + wsum[3]) * inv_count);
}

extern "C" void kernel_launch(void* const* d_in, const int* in_sizes, int n_in,
                              void* d_out, int out_size, void* d_ws, size_t ws_size,
                              hipStream_t stream) {
    const float* img1 = (const float*)d_in[0];
    const float* img2 = (const float*)d_in[1];
    float* out = (float*)d_out;

    float* fields   = (float*)d_ws;                    // 20*S floats (167.8 MB)
    float* partials = fields + 20 * (size_t)S;         // 4096 floats

    ssimA<<<4096, 64, 0, stream>>>(img1, img2, fields);
    ssimB<<<4096, 64, 0, stream>>>(fields, partials);
    ssim_final<<<1, 256, 0, stream>>>(partials, 4096, out,
                                      1.0 / ((double)S * 4));
}

// Round 10
// 181.400 us; speedup vs baseline: 1.9426x; 1.9426x over previous
//
#include <hip/hip_runtime.h>

// SSIM3D, (4,1,128,128,128) fp32, separable 11-tap Gaussian, scalar mean out.
//
// R16 == R15 resubmit (R15 hit "container failed twice" -- no verdict; same
// infra signature as R7, which passed verbatim on resubmit. Audit of the
// write-2-ahead ring found no OOB/alignment/hazard: read slot t&3 vs write
// slot (t+2)&3 disjoint every step; max LDS dword 1260 < 1280).
//
// R15. R14 post-mortem: (64,4) gave VGPR cap 64 -> spills -> 202us. The arg2
// "law" is untrustworthy; ONLY (128,2)=128 VGPR/no-spill is proven (R6/R10/
// R13). Model from R10/R13 counters (3-way consistent): ~4.8/16 waves
// resident per CU, each ~65% stalled; DS BW only ~21% used (why R13's
// b32->b64 was a no-op). Fixes this round, all at (128,2):
//  1) A grid 2048->4096 (y-chunk 32->16): 32 waves/CU queued (residency
//     experiment; +24% row work is the price).
//  2) Write-2-AHEAD LDS ring (4 slots): load row t -> write t+2 -> read t+4;
//     ds_write->ds_read slack goes 0 -> 2 steps.
//  3) B thinned to 128-thread blocks (1 y-row each, grid 2048), schedule
//     unchanged.
// Invariants: ssimA WRITE_SIZE ~= 164MB (no scratch), VGPR <= 128.
// Decision rule: occupancy still ~15% AND dur >= 75us -> residency cap is
// structural -> delete A's LDS next round.

#define SLICE (128*128)        // 16384
#define S  (128*SLICE)         // 2097152 per field per batch
#define ZROW 640               // 5 fields * 128 x  (interleaved row)
#define ZSL  81920             // 128 y * ZROW      (interleaved slice)
#define C1_ 0.0001f
#define C2_ 0.0009f

__device__ __forceinline__ void make_g_s(float* gs) {
    float g[11]; float s = 0.f;
#pragma unroll
    for (int i = 0; i < 11; ++i) {
        float d = (float)(i - 5);
        g[i] = __expf(-d * d / 4.5f);
        s += g[i];
    }
    float inv = 1.f / s;
#pragma unroll
    for (int i = 0; i < 11; ++i)
        gs[i] = __int_as_float(__builtin_amdgcn_readfirstlane(
                    __float_as_int(g[i] * inv)));
}

// ---------------- Kernel A: x-conv + y-conv, walk y ----------------
// grid: 4n * 128z * 8yc = 4096 blocks of 128 threads (2 independent waves).
// Thread owns x = tid; walks 16 y outputs (26 input rows, fully unrolled).
// Per-wave LDS ring: 4 slots x (img1 row | img2 row), rows padded to 160
// floats (data at dwords [8..135], zeros outside): maskless 11-tap.
// Pipeline: global load row(t+4) issued at t; LDS-write of row(t+2) (loaded
// at t-2) at t; reads of slot t&3 (written at t-2). vm and lgkm slack = 2
// steps each.
#define RB    160              // dwords per padded row
#define RSLOT (2*RB)           // 320 dwords per ring slot
#define WRING (4*RSLOT)        // 1280 dwords per wave ring (4 slots) = 5 KiB

// One pipeline step. T_ compile-time step index, TM_ == T_ % 11,
// J0_/J1_ compile-time y-tap range, STORE_/OKC_ flags.
#define STEPA(T_, TM_, J0_, J1_, STORE_, OKC_) do {                           \
    const int T__ = (T_);                                                     \
    int sp__ = T__ + 4; if (sp__ > 25) sp__ = 25;                             \
    int rowc__ = min(max(y0 + sp__ - 5, 0), 127);                             \
    float4 Rn__ = *(const float4*)(src + (size_t)rowc__ * 128);               \
    if (OKC_) {                                                               \
        const float* rp__ = p_rd + ((T_) & 3) * RSLOT;                        \
        float u1__ = 0.f, u2__ = 0.f, a11__ = 0.f, a22__ = 0.f, a12__ = 0.f;  \
        _Pragma("unroll")                                                     \
        for (int j = 0; j < 6; ++j) {                                         \
            float2 va__ = *(const float2*)(rp__ + 2 * j);                     \
            float2 vb__ = *(const float2*)(rp__ + RB + 2 * j);                \
            {                                                                 \
                float wj__ = w12[2 * j];                                      \
                float ta__ = wj__ * va__.x, tb__ = wj__ * vb__.x;             \
                u1__ += ta__; u2__ += tb__;                                   \
                a11__ = fmaf(ta__, va__.x, a11__);                            \
                a12__ = fmaf(ta__, vb__.x, a12__);                            \
                a22__ = fmaf(tb__, vb__.x, a22__);                            \
            }                                                                 \
            {                                                                 \
                float wj__ = w12[2 * j + 1];                                  \
                float ta__ = wj__ * va__.y, tb__ = wj__ * vb__.y;             \
                u1__ += ta__; u2__ += tb__;                                   \
                a11__ = fmaf(ta__, va__.y, a11__);                            \
                a12__ = fmaf(ta__, vb__.y, a12__);                            \
                a22__ = fmaf(tb__, vb__.y, a22__);                            \
            }                                                                 \
        }                                                                     \
        _Pragma("unroll")                                                     \
        for (int j = (J0_); j <= (J1_); ++j) {                                \
            const int sl__ = ((TM_) + j + 1) % 11;                            \
            float wy__ = gs[10 - j];                                          \
            acc[0][sl__] = fmaf(wy__, u1__,  acc[0][sl__]);                   \
            acc[1][sl__] = fmaf(wy__, u2__,  acc[1][sl__]);                   \
            acc[2][sl__] = fmaf(wy__, a11__, acc[2][sl__]);                   \
            acc[3][sl__] = fmaf(wy__, a22__, acc[3][sl__]);                   \
            acc[4][sl__] = fmaf(wy__, a12__, acc[4][sl__]);                   \
        }                                                                     \
    }                                                                         \
    *(float4*)(p_wr + (((T_) + 2) & 3) * RSLOT) = h1;  /* row T+2 */          \
    if (STORE_) {                                                             \
        size_t wo__ = (size_t)(y0 + T__ - 10) * ZROW;                         \
        const int es__ = ((TM_) + 1) % 11;                                    \
        _Pragma("unroll")                                                     \
        for (int f = 0; f < 5; ++f) {                                         \
            fb[wo__ + f * 128] = acc[f][es__];                                \
            acc[f][es__] = 0.f;                                               \
        }                                                                     \
    }                                                                         \
    h1 = h2; h2 = Rn__;                                                       \
} while (0)

__global__ __launch_bounds__(128, 2)
void ssimA(const float* __restrict__ img1, const float* __restrict__ img2,
           float* __restrict__ fields) {
    __shared__ __align__(16) float ring[2 * WRING];   // 10 KiB (2 waves)
    float gs[11]; make_g_s(gs);
    const int x = threadIdx.x;                 // 0..127 (output column)
    const int w = x >> 6, l = x & 63;          // wave, lane
    const int b = blockIdx.x;
    const int yc = b & 7, z = (b >> 3) & 127, n = b >> 10;
    const int y0 = yc * 16;
    // lanes 0-31 stage the img1 row (float4 each), lanes 32-63 the img2 row
    const float* src = (l < 32 ? img1 : img2)
                     + (size_t)n * S + (size_t)z * SLICE + 4 * (l & 31);
    float* fb = fields + (size_t)(n * 128 + z) * ZSL + x;

    // per-parity 12-tap weights over the aligned window [e, e+11],
    // e = (x-5)&~1, p = (x-5)&1; tap k has weight g[k-p] (0 outside 0..10).
    const int p = (x - 5) & 1;
    const int e = (x - 5) - p;                 // even, in [-6, 122]
    float w12[12];
#pragma unroll
    for (int k = 0; k < 12; ++k) {
        float we = (k <= 10) ? gs[k] : 0.f;            // p == 0
        float wo = (k >= 1) ? gs[k - 1] : 0.f;         // p == 1
        w12[k] = p ? wo : we;
    }

    float* wring = ring + w * WRING;           // private per-wave ring
    float* p_rd = wring + (8 + e);             // aligned window base (8B)
    float* p_wr = wring + ((l < 32) ? 0 : RB) + 8 + 4 * (l & 31);

    // zero whole ring once: pads stay zero forever (x-boundary = free)
    for (int i = l; i < WRING; i += 64) wring[i] = 0.f;

    float acc[5][11];
#pragma unroll
    for (int f = 0; f < 5; ++f)
#pragma unroll
        for (int s2 = 0; s2 < 11; ++s2) acc[f][s2] = 0.f;

    // prologue: slots 0,1 <- rows for steps 0,1; h1,h2 <- rows for steps 2,3
    float4 h1, h2;
    {
        int r0 = min(max(y0 - 5, 0), 127);
        int r1 = min(max(y0 - 4, 0), 127);
        int r2 = min(max(y0 - 3, 0), 127);
        int r3 = min(max(y0 - 2, 0), 127);
        float4 R0 = *(const float4*)(src + (size_t)r0 * 128);
        float4 R1 = *(const float4*)(src + (size_t)r1 * 128);
        h1        = *(const float4*)(src + (size_t)r2 * 128);
        h2        = *(const float4*)(src + (size_t)r3 * 128);
        *(float4*)(p_wr)         = R0;         // slot 0
        *(float4*)(p_wr + RSLOT) = R1;         // slot 1
    }

    // head: t = 0..9 (partial y-window, row may be < 0; no stores)
#pragma unroll
    for (int t = 0; t < 10; ++t)
        STEPA(t, t, 10 - t, 10, false, (y0 + t - 5 >= 0));
    // mid: t = 10..15 -- full window, store every step
#pragma unroll
    for (int t = 10; t < 16; ++t)
        STEPA(t, t % 11, 0, 10, true, true);
    // drain: t = 16..25 (tail taps; row may be > 127 only at yc=7; store)
#pragma unroll
    for (int t = 16; t < 26; ++t)
        STEPA(t, t % 11, 0, 25 - t, true, (y0 + t - 5 < 128));
}

// ---------------- Kernel B: z-conv + map + reduce, walk z ----------------
// grid: 4n * 128y * 4zc = 2048 blocks of 128 threads (2 waves, 1 y-row).
// Thread owns x = tid; walks 32 z outputs. Batches reversed (freshest A
// output first -> L3 hits). Depth-4 prefetch; interleaved layout puts the
// 5 per-step loads in one 2560 B cluster.
#define STEPB(T_, TM_, J0_, J1_, STORE_, OKC_) do {                           \
    const int T__ = (T_);                                                     \
    int sp__ = T__ + 4; if (sp__ > 41) sp__ = 41;                             \
    size_t off__ = (size_t)min(max(z0 + sp__ - 5, 0), 127) * ZSL;             \
    float N0__ = base[off__];                                                 \
    float N1__ = base[off__ + 128];                                           \
    float N2__ = base[off__ + 256];                                           \
    float N3__ = base[off__ + 384];                                           \
    float N4__ = base[off__ + 512];                                           \
    if (OKC_) {                                                               \
        _Pragma("unroll")                                                     \
        for (int j = (J0_); j <= (J1_); ++j) {                                \
            const int sl__ = ((TM_) + j + 1) % 11;                            \
            float wz__ = gs[10 - j];                                          \
            acc[0][sl__] = fmaf(wz__, P0[0], acc[0][sl__]);                   \
            acc[1][sl__] = fmaf(wz__, P0[1], acc[1][sl__]);                   \
            acc[2][sl__] = fmaf(wz__, P0[2], acc[2][sl__]);                   \
            acc[3][sl__] = fmaf(wz__, P0[3], acc[3][sl__]);                   \
            acc[4][sl__] = fmaf(wz__, P0[4], acc[4][sl__]);                   \
        }                                                                     \
    }                                                                         \
    if (STORE_) {                                                             \
        const int es__ = ((TM_) + 1) % 11;                                    \
        float m1__ = acc[0][es__], m2__ = acc[1][es__];                       \
        float p11__ = acc[2][es__], p22__ = acc[3][es__], p12__ = acc[4][es__];\
        float m1s__ = m1__ * m1__, m2s__ = m2__ * m2__, m12__ = m1__ * m2__;  \
        float v1c__ = p11__ - m1s__, v2c__ = p22__ - m2s__, cv__ = p12__ - m12__;\
        float num__ = (2.f * m12__ + C1_) * (2.f * cv__ + C2_);               \
        float den__ = (m1s__ + m2s__ + C1_) * (v1c__ + v2c__ + C2_);          \
        sum += num__ / den__;                                                 \
        _Pragma("unroll")                                                     \
        for (int f = 0; f < 5; ++f) acc[f][es__] = 0.f;                       \
    }                                                                         \
    _Pragma("unroll")                                                         \
    for (int f = 0; f < 5; ++f) { P0[f] = P1[f]; P1[f] = P2[f]; P2[f] = P3[f]; } \
    P3[0] = N0__; P3[1] = N1__; P3[2] = N2__; P3[3] = N3__; P3[4] = N4__;     \
} while (0)

__global__ __launch_bounds__(128, 2)
void ssimB(const float* __restrict__ fields, float* __restrict__ partials) {
    float gs[11]; make_g_s(gs);
    const int tid = threadIdx.x;
    const int x = tid;                          // 0..127
    const int b = blockIdx.x;
    const int zc = b & 3, y = (b >> 2) & 127;
    const int n = 3 - (b >> 9);                 // reverse batches (L3 hits)
    const int z0 = zc * 32;
    const float* base = fields + (size_t)n * 128 * ZSL + (size_t)y * ZROW + x;

    float acc[5][11];
#pragma unroll
    for (int f = 0; f < 5; ++f)
#pragma unroll
        for (int s2 = 0; s2 < 11; ++s2) acc[f][s2] = 0.f;

    float sum = 0.f;

    // depth-4 prologue: slices for steps 0..3
    float P0[5], P1[5], P2[5], P3[5];
    {
        size_t o0 = (size_t)min(max(z0 - 5, 0), 127) * ZSL;
        size_t o1 = (size_t)min(max(z0 - 4, 0), 127) * ZSL;
        size_t o2 = (size_t)min(max(z0 - 3, 0), 127) * ZSL;
        size_t o3 = (size_t)min(max(z0 - 2, 0), 127) * ZSL;
#pragma unroll
        for (int f = 0; f < 5; ++f) {
            P0[f] = base[o0 + f * 128];
            P1[f] = base[o1 + f * 128];
            P2[f] = base[o2 + f * 128];
            P3[f] = base[o3 + f * 128];
        }
    }

    // head: t = 0..9
#pragma unroll
    for (int t = 0; t < 10; ++t)
        STEPB(t, t, 10 - t, 10, false, (z0 + t - 5 >= 0));
    // steady: t = 10..31 -- branch-free
#pragma unroll 1
    for (int blk = 0; blk < 2; ++blk) {
#pragma unroll
        for (int tt = 0; tt < 11; ++tt)
            STEPB(10 + blk * 11 + tt, (10 + tt) % 11, 0, 10, true, true);
    }
    // drain: t = 32..41
#pragma unroll
    for (int t = 32; t < 42; ++t)
        STEPB(t, t % 11, 0, 41 - t, true, (z0 + t - 5 < 128));

    // 2-wave reduce
#pragma unroll
    for (int o = 32; o > 0; o >>= 1) sum += __shfl_down(sum, o, 64);
    __shared__ float ws2[2];
    if ((tid & 63) == 0) ws2[tid >> 6] = sum;
    __syncthreads();
    if (tid == 0) partials[blockIdx.x] = ws2[0] + ws2[1];
}

// ---------------- final reduce ----------------
__global__ void ssim_final(const float* __restrict__ partial, int n,
                           float* __restrict__ out, double inv_count) {
    int tid = threadIdx.x;
    double s = 0.0;
    for (int i = tid; i < n; i += 256) s += (double)partial[i];
#pragma unroll
    for (int o = 32; o > 0; o >>= 1) s += __shfl_down(s, o, 64);
    __shared__ double wsum[4];
    int lane = tid & 63, wid = tid >> 6;
    if (lane == 0) wsum[wid] = s;
    __syncthreads();
    if (tid == 0)
        out[0] = (float)((wsum[0] + wsum[1] + wsum[2] + wsum[3]) * inv_count);
}

extern "C" void kernel_launch(void* const* d_in, const int* in_sizes, int n_in,
                              void* d_out, int out_size, void* d_ws, size_t ws_size,
                              hipStream_t stream) {
    const float* img1 = (const float*)d_in[0];
    const float* img2 = (const float*)d_in[1];
    float* out = (float*)d_out;

    float* fields   = (float*)d_ws;                    // 20*S floats (167.8 MB)
    float* partials = fields + 20 * (size_t)S;         // 2048 floats

    ssimA<<<4096, 128, 0, stream>>>(img1, img2, fields);
    ssimB<<<2048, 128, 0, stream>>>(fields, partials);
    ssim_final<<<1, 256, 0, stream>>>(partials, 2048, out,
                                      1.0 / ((double)S * 4));
}

// Round 11
// 176.230 us; speedup vs baseline: 1.9996x; 1.0293x over previous
//
#include <hip/hip_runtime.h>

// SSIM3D, (4,1,128,128,128) fp32, separable 11-tap Gaussian, scalar mean out.
//
// R17: 4-FIELD REDUCTION (exact algebra). SSIM uses sigma1^2+sigma2^2 only
// as a SUM; conv is linear -> conv(a^2)+conv(b^2) = conv(a^2+b^2). Fields
// become (conv a, conv b, conv(a^2+b^2), conv ab): A writes 131 MB (-20%),
// A x-conv 7 ops/tap (-22%), B 4 loads/step, acc[4][11].
// R16 post-mortem: A=73us at 2.25 TB/s pure writes (~70% of achievable
// write stream) -> WRITE-BOUND; occupancy pinned ~17% regardless of grid
// (not VGPR/LDS-limited; structural). B ~100us latency-bound -> prefetch
// depth 4->6 (state ~100 regs, fits the proven 128 cap).
// A structure otherwise byte-identical to R16 (write-2-ahead ring, y-chunk
// 16, (128,2)). Invariants: A WRITE_SIZE == 131072 KB, VGPR <= 128.
// Decision rule: A dur ~73 despite -20% write AND -20% VALU -> models wrong
// -> fused single-kernel next round.

#define SLICE (128*128)        // 16384
#define S  (128*SLICE)         // 2097152 per field per batch
#define ZROW 512               // 4 fields * 128 x  (interleaved row)
#define ZSL  65536             // 128 y * ZROW      (interleaved slice)
#define C1_ 0.0001f
#define C2_ 0.0009f

__device__ __forceinline__ void make_g_s(float* gs) {
    float g[11]; float s = 0.f;
#pragma unroll
    for (int i = 0; i < 11; ++i) {
        float d = (float)(i - 5);
        g[i] = __expf(-d * d / 4.5f);
        s += g[i];
    }
    float inv = 1.f / s;
#pragma unroll
    for (int i = 0; i < 11; ++i)
        gs[i] = __int_as_float(__builtin_amdgcn_readfirstlane(
                    __float_as_int(g[i] * inv)));
}

// ---------------- Kernel A: x-conv + y-conv, walk y ----------------
// grid: 4n * 128z * 8yc = 4096 blocks of 128 threads (2 independent waves).
// Thread owns x = tid; walks 16 y outputs (26 input rows, fully unrolled).
// Per-wave LDS ring: 4 slots x (img1 row | img2 row), rows padded to 160
// floats (data at dwords [8..135], zeros outside): maskless 11-tap.
// Pipeline: global load row(t+4) at t; LDS-write row(t+2) at t; read slot
// t&3 (written t-2). Fields: u1=conv(a), u2=conv(b), ss=conv(a^2+b^2),
// a12=conv(ab).
#define RB    160              // dwords per padded row
#define RSLOT (2*RB)           // 320 dwords per ring slot
#define WRING (4*RSLOT)        // 1280 dwords per wave ring (4 slots) = 5 KiB

#define STEPA(T_, TM_, J0_, J1_, STORE_, OKC_) do {                           \
    const int T__ = (T_);                                                     \
    int sp__ = T__ + 4; if (sp__ > 25) sp__ = 25;                             \
    int rowc__ = min(max(y0 + sp__ - 5, 0), 127);                             \
    float4 Rn__ = *(const float4*)(src + (size_t)rowc__ * 128);               \
    if (OKC_) {                                                               \
        const float* rp__ = p_rd + ((T_) & 3) * RSLOT;                        \
        float u1__ = 0.f, u2__ = 0.f, ss__ = 0.f, a12__ = 0.f;                \
        _Pragma("unroll")                                                     \
        for (int j = 0; j < 6; ++j) {                                         \
            float2 va__ = *(const float2*)(rp__ + 2 * j);                     \
            float2 vb__ = *(const float2*)(rp__ + RB + 2 * j);                \
            {                                                                 \
                float wj__ = w12[2 * j];                                      \
                float ta__ = wj__ * va__.x, tb__ = wj__ * vb__.x;             \
                u1__ += ta__; u2__ += tb__;                                   \
                ss__  = fmaf(ta__, va__.x, ss__);                             \
                ss__  = fmaf(tb__, vb__.x, ss__);                             \
                a12__ = fmaf(ta__, vb__.x, a12__);                            \
            }                                                                 \
            {                                                                 \
                float wj__ = w12[2 * j + 1];                                  \
                float ta__ = wj__ * va__.y, tb__ = wj__ * vb__.y;             \
                u1__ += ta__; u2__ += tb__;                                   \
                ss__  = fmaf(ta__, va__.y, ss__);                             \
                ss__  = fmaf(tb__, vb__.y, ss__);                             \
                a12__ = fmaf(ta__, vb__.y, a12__);                            \
            }                                                                 \
        }                                                                     \
        _Pragma("unroll")                                                     \
        for (int j = (J0_); j <= (J1_); ++j) {                                \
            const int sl__ = ((TM_) + j + 1) % 11;                            \
            float wy__ = gs[10 - j];                                          \
            acc[0][sl__] = fmaf(wy__, u1__,  acc[0][sl__]);                   \
            acc[1][sl__] = fmaf(wy__, u2__,  acc[1][sl__]);                   \
            acc[2][sl__] = fmaf(wy__, ss__,  acc[2][sl__]);                   \
            acc[3][sl__] = fmaf(wy__, a12__, acc[3][sl__]);                   \
        }                                                                     \
    }                                                                         \
    *(float4*)(p_wr + (((T_) + 2) & 3) * RSLOT) = h1;  /* row T+2 */          \
    if (STORE_) {                                                             \
        size_t wo__ = (size_t)(y0 + T__ - 10) * ZROW;                         \
        const int es__ = ((TM_) + 1) % 11;                                    \
        _Pragma("unroll")                                                     \
        for (int f = 0; f < 4; ++f) {                                         \
            fb[wo__ + f * 128] = acc[f][es__];                                \
            acc[f][es__] = 0.f;                                               \
        }                                                                     \
    }                                                                         \
    h1 = h2; h2 = Rn__;                                                       \
} while (0)

__global__ __launch_bounds__(128, 2)
void ssimA(const float* __restrict__ img1, const float* __restrict__ img2,
           float* __restrict__ fields) {
    __shared__ __align__(16) float ring[2 * WRING];   // 10 KiB (2 waves)
    float gs[11]; make_g_s(gs);
    const int x = threadIdx.x;                 // 0..127 (output column)
    const int w = x >> 6, l = x & 63;          // wave, lane
    const int b = blockIdx.x;
    const int yc = b & 7, z = (b >> 3) & 127, n = b >> 10;
    const int y0 = yc * 16;
    // lanes 0-31 stage the img1 row (float4 each), lanes 32-63 the img2 row
    const float* src = (l < 32 ? img1 : img2)
                     + (size_t)n * S + (size_t)z * SLICE + 4 * (l & 31);
    float* fb = fields + (size_t)(n * 128 + z) * ZSL + x;

    // per-parity 12-tap weights over the aligned window [e, e+11],
    // e = (x-5)&~1, p = (x-5)&1; tap k has weight g[k-p] (0 outside 0..10).
    const int p = (x - 5) & 1;
    const int e = (x - 5) - p;                 // even, in [-6, 122]
    float w12[12];
#pragma unroll
    for (int k = 0; k < 12; ++k) {
        float we = (k <= 10) ? gs[k] : 0.f;            // p == 0
        float wo = (k >= 1) ? gs[k - 1] : 0.f;         // p == 1
        w12[k] = p ? wo : we;
    }

    float* wring = ring + w * WRING;           // private per-wave ring
    float* p_rd = wring + (8 + e);             // aligned window base (8B)
    float* p_wr = wring + ((l < 32) ? 0 : RB) + 8 + 4 * (l & 31);

    // zero whole ring once: pads stay zero forever (x-boundary = free)
    for (int i = l; i < WRING; i += 64) wring[i] = 0.f;

    float acc[4][11];
#pragma unroll
    for (int f = 0; f < 4; ++f)
#pragma unroll
        for (int s2 = 0; s2 < 11; ++s2) acc[f][s2] = 0.f;

    // prologue: slots 0,1 <- rows for steps 0,1; h1,h2 <- rows for steps 2,3
    float4 h1, h2;
    {
        int r0 = min(max(y0 - 5, 0), 127);
        int r1 = min(max(y0 - 4, 0), 127);
        int r2 = min(max(y0 - 3, 0), 127);
        int r3 = min(max(y0 - 2, 0), 127);
        float4 R0 = *(const float4*)(src + (size_t)r0 * 128);
        float4 R1 = *(const float4*)(src + (size_t)r1 * 128);
        h1        = *(const float4*)(src + (size_t)r2 * 128);
        h2        = *(const float4*)(src + (size_t)r3 * 128);
        *(float4*)(p_wr)         = R0;         // slot 0
        *(float4*)(p_wr + RSLOT) = R1;         // slot 1
    }

    // head: t = 0..9 (partial y-window, row may be < 0; no stores)
#pragma unroll
    for (int t = 0; t < 10; ++t)
        STEPA(t, t, 10 - t, 10, false, (y0 + t - 5 >= 0));
    // mid: t = 10..15 -- full window, store every step
#pragma unroll
    for (int t = 10; t < 16; ++t)
        STEPA(t, t % 11, 0, 10, true, true);
    // drain: t = 16..25 (tail taps; row may be > 127 only at yc=7; store)
#pragma unroll
    for (int t = 16; t < 26; ++t)
        STEPA(t, t % 11, 0, 25 - t, true, (y0 + t - 5 < 128));
}

// ---------------- Kernel B: z-conv + map + reduce, walk z ----------------
// grid: 4n * 128y * 4zc = 2048 blocks of 128 threads (2 waves, 1 y-row).
// Thread owns x = tid; walks 32 z outputs. Batches reversed (freshest A
// output first -> L3 hits). Depth-6 prefetch (P0..P5, 24 regs); interleaved
// layout: the 4 per-step loads sit in one 2048 B cluster.
#define STEPB(T_, TM_, J0_, J1_, STORE_, OKC_) do {                           \
    const int T__ = (T_);                                                     \
    int sp__ = T__ + 6; if (sp__ > 41) sp__ = 41;                             \
    size_t off__ = (size_t)min(max(z0 + sp__ - 5, 0), 127) * ZSL;             \
    float N0__ = base[off__];                                                 \
    float N1__ = base[off__ + 128];                                           \
    float N2__ = base[off__ + 256];                                           \
    float N3__ = base[off__ + 384];                                           \
    if (OKC_) {                                                               \
        _Pragma("unroll")                                                     \
        for (int j = (J0_); j <= (J1_); ++j) {                                \
            const int sl__ = ((TM_) + j + 1) % 11;                            \
            float wz__ = gs[10 - j];                                          \
            acc[0][sl__] = fmaf(wz__, P0[0], acc[0][sl__]);                   \
            acc[1][sl__] = fmaf(wz__, P0[1], acc[1][sl__]);                   \
            acc[2][sl__] = fmaf(wz__, P0[2], acc[2][sl__]);                   \
            acc[3][sl__] = fmaf(wz__, P0[3], acc[3][sl__]);                   \
        }                                                                     \
    }                                                                         \
    if (STORE_) {                                                             \
        const int es__ = ((TM_) + 1) % 11;                                    \
        float m1__ = acc[0][es__], m2__ = acc[1][es__];                       \
        float ps__ = acc[2][es__], p12__ = acc[3][es__];                      \
        float m1s__ = m1__ * m1__, m2s__ = m2__ * m2__, m12__ = m1__ * m2__;  \
        float v12__ = ps__ - m1s__ - m2s__;     /* sigma1^2 + sigma2^2 */     \
        float cv__  = p12__ - m12__;            /* sigma12 */                 \
        float num__ = (2.f * m12__ + C1_) * (2.f * cv__ + C2_);               \
        float den__ = (m1s__ + m2s__ + C1_) * (v12__ + C2_);                  \
        sum += num__ / den__;                                                 \
        _Pragma("unroll")                                                     \
        for (int f = 0; f < 4; ++f) acc[f][es__] = 0.f;                       \
    }                                                                         \
    _Pragma("unroll")                                                         \
    for (int f = 0; f < 4; ++f) {                                             \
        P0[f] = P1[f]; P1[f] = P2[f]; P2[f] = P3[f];                          \
        P3[f] = P4[f]; P4[f] = P5[f];                                         \
    }                                                                         \
    P5[0] = N0__; P5[1] = N1__; P5[2] = N2__; P5[3] = N3__;                   \
} while (0)

__global__ __launch_bounds__(128, 2)
void ssimB(const float* __restrict__ fields, float* __restrict__ partials) {
    float gs[11]; make_g_s(gs);
    const int tid = threadIdx.x;
    const int x = tid;                          // 0..127
    const int b = blockIdx.x;
    const int zc = b & 3, y = (b >> 2) & 127;
    const int n = 3 - (b >> 9);                 // reverse batches (L3 hits)
    const int z0 = zc * 32;
    const float* base = fields + (size_t)n * 128 * ZSL + (size_t)y * ZROW + x;

    float acc[4][11];
#pragma unroll
    for (int f = 0; f < 4; ++f)
#pragma unroll
        for (int s2 = 0; s2 < 11; ++s2) acc[f][s2] = 0.f;

    float sum = 0.f;

    // depth-6 prologue: slices for steps 0..5 (z0-5 .. z0)
    float P0[4], P1[4], P2[4], P3[4], P4[4], P5[4];
    {
        size_t o0 = (size_t)min(max(z0 - 5, 0), 127) * ZSL;
        size_t o1 = (size_t)min(max(z0 - 4, 0), 127) * ZSL;
        size_t o2 = (size_t)min(max(z0 - 3, 0), 127) * ZSL;
        size_t o3 = (size_t)min(max(z0 - 2, 0), 127) * ZSL;
        size_t o4 = (size_t)min(max(z0 - 1, 0), 127) * ZSL;
        size_t o5 = (size_t)min(max(z0 - 0, 0), 127) * ZSL;
#pragma unroll
        for (int f = 0; f < 4; ++f) {
            P0[f] = base[o0 + f * 128];
            P1[f] = base[o1 + f * 128];
            P2[f] = base[o2 + f * 128];
            P3[f] = base[o3 + f * 128];
            P4[f] = base[o4 + f * 128];
            P5[f] = base[o5 + f * 128];
        }
    }

    // head: t = 0..9
#pragma unroll
    for (int t = 0; t < 10; ++t)
        STEPB(t, t, 10 - t, 10, false, (z0 + t - 5 >= 0));
    // steady: t = 10..31 -- branch-free
#pragma unroll 1
    for (int blk = 0; blk < 2; ++blk) {
#pragma unroll
        for (int tt = 0; tt < 11; ++tt)
            STEPB(10 + blk * 11 + tt, (10 + tt) % 11, 0, 10, true, true);
    }
    // drain: t = 32..41
#pragma unroll
    for (int t = 32; t < 42; ++t)
        STEPB(t, t % 11, 0, 41 - t, true, (z0 + t - 5 < 128));

    // 2-wave reduce
#pragma unroll
    for (int o = 32; o > 0; o >>= 1) sum += __shfl_down(sum, o, 64);
    __shared__ float ws2[2];
    if ((tid & 63) == 0) ws2[tid >> 6] = sum;
    __syncthreads();
    if (tid == 0) partials[blockIdx.x] = ws2[0] + ws2[1];
}

// ---------------- final reduce ----------------
__global__ void ssim_final(const float* __restrict__ partial, int n,
                           float* __restrict__ out, double inv_count) {
    int tid = threadIdx.x;
    double s = 0.0;
    for (int i = tid; i < n; i += 256) s += (double)partial[i];
#pragma unroll
    for (int o = 32; o > 0; o >>= 1) s += __shfl_down(s, o, 64);
    __shared__ double wsum[4];
    int lane = tid & 63, wid = tid >> 6;
    if (lane == 0) wsum[wid] = s;
    __syncthreads();
    if (tid == 0)
        out[0] = (float)((wsum[0] + wsum[1] + wsum[2] + wsum[3]) * inv_count);
}

extern "C" void kernel_launch(void* const* d_in, const int* in_sizes, int n_in,
                              void* d_out, int out_size, void* d_ws, size_t ws_size,
                              hipStream_t stream) {
    const float* img1 = (const float*)d_in[0];
    const float* img2 = (const float*)d_in[1];
    float* out = (float*)d_out;

    float* fields   = (float*)d_ws;                    // 16*S floats (134 MB)
    float* partials = fields + 16 * (size_t)S;         // 2048 floats

    ssimA<<<4096, 128, 0, stream>>>(img1, img2, fields);
    ssimB<<<2048, 128, 0, stream>>>(fields, partials);
    ssim_final<<<1, 256, 0, stream>>>(partials, 2048, out,
                                      1.0 / ((double)S * 4));
}